// Round 2
// baseline (383.831 us; speedup 1.0000x reference)
//
#include <hip/hip_runtime.h>
#include <hip/hip_bf16.h>

// Problem constants (T=2048, B=8, C=512, O=512, RD=64, NE=8, tau=1, commit=0.1)
// All inputs/outputs are float32 (reference dtype). MoE GEMM runs bf16 MFMA on
// converted copies in ws; GMM assignment + loss stay f32.
#define NROWS 16384
#define CC 512
#define OO 512
#define RDIM 64
#define NE 8
#define NEXP 9            // 8 experts + bias_w as expert 8 (scale 1.0)
#define COMMIT_SCALE 0.1f
#define LOG2PI_TERM 58.81206612509905f   // (RD/2)*log(2*pi*tau), tau=1

typedef __attribute__((ext_vector_type(8))) short short8;
typedef __attribute__((ext_vector_type(4))) float f32x4;

__device__ __forceinline__ unsigned short f2bf(float f) {
  unsigned int u = __float_as_uint(f);
  u += 0x7fffu + ((u >> 16) & 1u);   // round-to-nearest-even
  return (unsigned short)(u >> 16);
}

// ---------------------------------------------------------------------------
// Kernel 0: convert f32 -> bf16 copies in ws (x, and [pw_w ; bias_w] stacked
// as 9 contiguous expert weight blocks).
// ---------------------------------------------------------------------------
#define X4 2097152u   // x float4 count      (8388608 / 4)
#define P4 524288u    // pw_w float4 count   (2097152 / 4)
#define B4 65536u     // bias_w float4 count (262144 / 4)

__global__ __launch_bounds__(256) void k_prep(
    const float* __restrict__ x, const float* __restrict__ pw,
    const float* __restrict__ bw,
    unsigned short* __restrict__ xb, unsigned short* __restrict__ wb)
{
  unsigned int i = blockIdx.x * 256 + threadIdx.x;   // float4 index
  const float* src;
  unsigned short* dst;
  if (i < X4)            { src = x  + (size_t)i * 4;            dst = xb + (size_t)i * 4; }
  else if (i < X4 + P4)  { size_t j = i - X4;  src = pw + j * 4; dst = wb + j * 4; }
  else                   { size_t j = i - X4 - P4; src = bw + j * 4; dst = wb + (size_t)P4 * 4 + j * 4; }
  float4 v = *(const float4*)src;
  ushort4 o;
  o.x = f2bf(v.x); o.y = f2bf(v.y); o.z = f2bf(v.z); o.w = f2bf(v.w);
  *(ushort4*)dst = o;
}

// ---------------------------------------------------------------------------
// Kernel 1: GMM responsibilities + loss (pure f32).
// One wave handles 4 rows; lane j owns k_j (RD == 64 == wave width).
// ---------------------------------------------------------------------------
__global__ __launch_bounds__(256) void k_assign(
    const float* __restrict__ x,      // [N, C]
    const float* __restrict__ map_w,  // [RD, C]
    const float* __restrict__ map_b,  // [RD]
    const float* __restrict__ cent,   // [NE, RD]
    const float* __restrict__ prior,  // [NE]
    float* __restrict__ resp_out,     // [N, NE] f32 (ws)
    float* __restrict__ loss_acc)     // [1] f32 (ws)
{
  __shared__ float lsum[4];
  const int tid  = threadIdx.x;
  const int wid  = tid >> 6;
  const int lane = tid & 63;
  const int row0 = blockIdx.x * 16 + wid * 4;

  const float4* wv = (const float4*)map_w + lane * (CC / 4);   // row `lane`
  const float4* xv = (const float4*)x + (size_t)row0 * (CC / 4);

  float a0 = 0.f, a1 = 0.f, a2 = 0.f, a3 = 0.f;
  #pragma unroll 4
  for (int i = 0; i < CC / 4; ++i) {
    float4 w = wv[i];
    float4 v0 = xv[i];
    a0 += v0.x * w.x + v0.y * w.y + v0.z * w.z + v0.w * w.w;
    float4 v1 = xv[i + 128];
    a1 += v1.x * w.x + v1.y * w.y + v1.z * w.z + v1.w * w.w;
    float4 v2 = xv[i + 256];
    a2 += v2.x * w.x + v2.y * w.y + v2.z * w.z + v2.w * w.w;
    float4 v3 = xv[i + 384];
    a3 += v3.x * w.x + v3.y * w.y + v3.z * w.z + v3.w * w.w;
  }
  const float mb = map_b[lane];
  float kk[4] = {a0 + mb, a1 + mb, a2 + mb, a3 + mb};

  // centroid column (lane j holds cent[e][j]), |c_e|^2, log prior
  float ce[8], c2[8], lp[8];
  #pragma unroll
  for (int e = 0; e < 8; ++e) {
    ce[e] = cent[e * RDIM + lane];
    float v = ce[e] * ce[e];
    #pragma unroll
    for (int off = 32; off; off >>= 1) v += __shfl_xor(v, off, 64);
    c2[e] = v;
    lp[e] = __logf(prior[e]);
  }

  float dsum = 0.f;
  #pragma unroll
  for (int r = 0; r < 4; ++r) {
    float k = kk[r];
    float v[9];
    v[0] = k * k;
    #pragma unroll
    for (int e = 0; e < 8; ++e) v[e + 1] = k * ce[e];
    #pragma unroll
    for (int off = 32; off; off >>= 1) {
      #pragma unroll
      for (int q = 0; q < 9; ++q) v[q] += __shfl_xor(v[q], off, 64);
    }
    float lr[8], mx = -3.4e38f;
    #pragma unroll
    for (int e = 0; e < 8; ++e) {
      float d2 = v[0] + c2[e] - 2.f * v[e + 1];
      lr[e] = -0.5f * d2 - LOG2PI_TERM + lp[e];
      mx = fmaxf(mx, lr[e]);
    }
    float s = 0.f;
    #pragma unroll
    for (int e = 0; e < 8; ++e) s += __expf(lr[e] - mx);
    float denom = mx + __logf(s);
    dsum += denom;
    float myv = 0.f;
    #pragma unroll
    for (int e = 0; e < 8; ++e) {
      float re = __expf(lr[e] - denom);
      myv = (lane == e) ? re : myv;
    }
    if (lane < 8) resp_out[(size_t)(row0 + r) * NE + lane] = myv;
  }
  if (lane == 0) lsum[wid] = dsum;
  __syncthreads();
  if (tid == 0) {
    float t = lsum[0] + lsum[1] + lsum[2] + lsum[3];
    atomicAdd(loss_acc, -COMMIT_SCALE * t);
  }
}

// ---------------------------------------------------------------------------
// Kernel 2: y = sum_e resp[:,e] * (x @ W_e^T)  (+ bias expert) + bias_b.
// 128x128 block tile, BK=32, 4 waves each 64x64 (4x4 frags of 16x16x32 bf16).
// Expert-outer with dual accumulator; inputs are the bf16 ws copies.
// ---------------------------------------------------------------------------
__global__ __launch_bounds__(256, 2) void k_moe(
    const unsigned short* __restrict__ xb,   // [N, C] bf16 (ws)
    const unsigned short* __restrict__ wb,   // [9, O, C] bf16 (ws)
    const float* __restrict__ bb,            // [O] f32
    const float* __restrict__ resp,          // [N, NE] f32 (ws)
    const float* __restrict__ loss_acc,      // [1] f32 (ws)
    float* __restrict__ out)                 // [N*O + 1] f32
{
  __shared__ unsigned short aT[128 * 40];    // 128 rows x 32 k, +8 pad
  __shared__ unsigned short bT[128 * 40];
  __shared__ float sc[NEXP * 128];

  const int tid = threadIdx.x;
  const int m0 = blockIdx.x * 128;
  const int o0 = blockIdx.y * 128;

  // stage resp scales: sc[e][row]; expert 8 (bias) = 1.0
  for (int idx = tid; idx < 128 * NE; idx += 256) {
    int r = idx >> 3, e = idx & 7;
    sc[e * 128 + r] = resp[(size_t)(m0 + r) * NE + e];
  }
  if (tid < 128) sc[8 * 128 + tid] = 1.0f;

  const int lane = tid & 63;
  const int wid = tid >> 6;
  const int wm = (wid & 1) * 64;
  const int wn = (wid >> 1) * 64;
  const int fr = lane & 15;      // A: m within tile / B: n within tile
  const int fq = lane >> 4;      // quad -> k chunk (*8), C/D row chunk (*4)

  const int srow = tid >> 1;            // staging row 0..127
  const int scol = (tid & 1) * 16;      // staging col 0 or 16
  const unsigned short* xrow = xb + (size_t)(m0 + srow) * CC + scol;

  f32x4 zero4 = {0.f, 0.f, 0.f, 0.f};
  f32x4 tot[4][4];
  #pragma unroll
  for (int i = 0; i < 4; ++i)
    #pragma unroll
    for (int j = 0; j < 4; ++j) tot[i][j] = zero4;

  for (int e = 0; e < NEXP; ++e) {
    const unsigned short* brow = wb + (size_t)e * OO * CC + (size_t)(o0 + srow) * CC + scol;

    f32x4 ae[4][4];
    #pragma unroll
    for (int i = 0; i < 4; ++i)
      #pragma unroll
      for (int j = 0; j < 4; ++j) ae[i][j] = zero4;

    for (int k0 = 0; k0 < CC; k0 += 32) {
      __syncthreads();   // protect LDS from previous iteration's readers
      *(uint4*)&aT[srow * 40 + scol]     = *(const uint4*)(xrow + k0);
      *(uint4*)&aT[srow * 40 + scol + 8] = *(const uint4*)(xrow + k0 + 8);
      *(uint4*)&bT[srow * 40 + scol]     = *(const uint4*)(brow + k0);
      *(uint4*)&bT[srow * 40 + scol + 8] = *(const uint4*)(brow + k0 + 8);
      __syncthreads();

      short8 af[4], bfr[4];
      #pragma unroll
      for (int i = 0; i < 4; ++i)
        af[i] = *(const short8*)&aT[(wm + i * 16 + fr) * 40 + fq * 8];
      #pragma unroll
      for (int j = 0; j < 4; ++j)
        bfr[j] = *(const short8*)&bT[(wn + j * 16 + fr) * 40 + fq * 8];

      #pragma unroll
      for (int i = 0; i < 4; ++i)
        #pragma unroll
        for (int j = 0; j < 4; ++j)
          ae[i][j] = __builtin_amdgcn_mfma_f32_16x16x32_bf16(af[i], bfr[j], ae[i][j], 0, 0, 0);
    }

    // tot += resp[row, e] * ae   (row = wm + i*16 + fq*4 + r)
    #pragma unroll
    for (int i = 0; i < 4; ++i) {
      float s[4];
      #pragma unroll
      for (int r = 0; r < 4; ++r) s[r] = sc[e * 128 + wm + i * 16 + fq * 4 + r];
      #pragma unroll
      for (int j = 0; j < 4; ++j)
        #pragma unroll
        for (int r = 0; r < 4; ++r) tot[i][j][r] += s[r] * ae[i][j][r];
    }
  }

  // epilogue: + bias_b, store f32
  #pragma unroll
  for (int j = 0; j < 4; ++j) {
    const int o = o0 + wn + j * 16 + fr;
    const float bias = bb[o];
    #pragma unroll
    for (int i = 0; i < 4; ++i) {
      #pragma unroll
      for (int r = 0; r < 4; ++r) {
        int m = m0 + wm + i * 16 + fq * 4 + r;
        out[(size_t)m * OO + o] = tot[i][j][r] + bias;
      }
    }
  }

  if (blockIdx.x == 0 && blockIdx.y == 0 && tid == 0)
    out[(size_t)NROWS * OO] = loss_acc[0];
}

extern "C" void kernel_launch(void* const* d_in, const int* in_sizes, int n_in,
                              void* d_out, int out_size, void* d_ws, size_t ws_size,
                              hipStream_t stream) {
  const float* x     = (const float*)d_in[0];
  // d_in[1] = key_feat (ignored by forward)
  const float* map_w = (const float*)d_in[2];
  const float* map_b = (const float*)d_in[3];
  const float* cent  = (const float*)d_in[4];
  const float* prior = (const float*)d_in[5];
  const float* pw    = (const float*)d_in[6];
  const float* bw    = (const float*)d_in[7];
  const float* bb    = (const float*)d_in[8];
  float* out = (float*)d_out;

  // ws layout
  char* wsp = (char*)d_ws;
  float* resp = (float*)wsp;                                   // [N*NE] f32 = 524288 B
  float* loss = (float*)(wsp + 524288);                        // [1] f32
  unsigned short* xb = (unsigned short*)(wsp + 524304);        // [N*C] bf16 = 16777216 B
  unsigned short* wb = (unsigned short*)(wsp + 524304 + 16777216); // [9*O*C] bf16 = 4718592 B

  hipMemsetAsync(loss, 0, sizeof(float), stream);
  k_prep<<<dim3((X4 + P4 + B4) / 256), dim3(256), 0, stream>>>(x, pw, bw, xb, wb);
  k_assign<<<dim3(NROWS / 16), dim3(256), 0, stream>>>(x, map_w, map_b, cent, prior, resp, loss);
  dim3 grid(NROWS / 128, OO / 128);
  k_moe<<<grid, dim3(256), 0, stream>>>(xb, wb, bb, resp, loss, out);
}